// Round 5
// baseline (1051.302 us; speedup 1.0000x reference)
//
#include <hip/hip_runtime.h>
#include <cstdint>
#include <cstddef>

#define INPUT_DIM 256
#define OUT_DIM   16
#define NMID      784     // middle nodes
#define NNODE     1040
#define MROW      768     // effM row length (middle cols; cols >=768 are in-block only)
#define KB        16      // node block size
#define NBLK      49      // 784 / 16
#define NMCH      24      // middle-state chunks of 32 k-elems (768/32)
#define BATCH     32768

typedef float f32x4 __attribute__((ext_vector_type(4)));
typedef float f32x8v __attribute__((ext_vector_type(8)));
typedef __bf16 bf16x8 __attribute__((ext_vector_type(8)));

#define GLL16(gp, lp)                                                        \
  __builtin_amdgcn_global_load_lds(                                          \
      (const __attribute__((address_space(1))) unsigned int*)(gp),           \
      (__attribute__((address_space(3))) unsigned int*)(lp), 16, 0, 0)

static __device__ __forceinline__ unsigned int f2bf(float f) {
  unsigned int u = __builtin_bit_cast(unsigned int, f);
  u += 0x7fffu + ((u >> 16) & 1u);   // round-to-nearest-even
  return u >> 16;
}
static __device__ __forceinline__ float bf2f(unsigned short h) {
  unsigned int u = ((unsigned int)h) << 16;
  return __builtin_bit_cast(float, u);
}
static __device__ __forceinline__ float bflo(unsigned int w) {
  return __builtin_bit_cast(float, w << 16);
}
static __device__ __forceinline__ float bfhi(unsigned int w) {
  return __builtin_bit_cast(float, w & 0xffff0000u);
}

// ---------------------------------------------------------------------------
// Prep 1: split masked weights into
//   effX[i][k]  = w[k][i]*conn[k][i]              (k<256, always causal), bf16
//   effM[i][jm] = w[256+jm][i]*conn*ex[jm]*(jm<i) (jm<768; jm>=768 is in-block
//                 for block 48 and handled by wtri), bf16
// ---------------------------------------------------------------------------
__global__ __launch_bounds__(256) void prep_efft(
    const float* __restrict__ w, const int* __restrict__ conn,
    const int* __restrict__ ex, unsigned short* __restrict__ effX,
    unsigned short* __restrict__ effM) {
  __shared__ unsigned short tile[64][66];
  const int j0 = blockIdx.x * 64;
  const int i0 = blockIdx.y * 64;
  const int tx = threadIdx.x & 63;   // i offset
  const int ty = threadIdx.x >> 6;   // j sub-row
  const int i  = i0 + tx;
  for (int t = 0; t < 16; ++t) {
    int j = j0 + t * 4 + ty;
    float v = 0.f;
    if (j < NNODE && i < NMID && j < INPUT_DIM + i) {
      float e = (j >= INPUT_DIM) ? (float)ex[j - INPUT_DIM] : 1.f;
      v = w[(size_t)j * NMID + i] * (float)conn[(size_t)j * NMID + i] * e;
    }
    tile[t * 4 + ty][tx] = (unsigned short)f2bf(v);
  }
  __syncthreads();
  const int i_loc = threadIdx.x >> 2;
  const int jq    = threadIdx.x & 3;
  const int iw    = i0 + i_loc;
  const int jbase = j0 + jq * 16;
  if (iw < NMID) {
    if (jbase + 16 <= INPUT_DIM) {
      #pragma unroll
      for (int c = 0; c < 16; ++c)
        effX[(size_t)iw * INPUT_DIM + jbase + c] = tile[jq * 16 + c][i_loc];
    } else if (jbase >= INPUT_DIM && (jbase - INPUT_DIM + 16) <= MROW) {
      #pragma unroll
      for (int c = 0; c < 16; ++c)
        effM[(size_t)iw * MROW + (jbase - INPUT_DIM) + c] =
            tile[jq * 16 + c][i_loc];
    }
  }
}

// ---------------------------------------------------------------------------
// Prep 2: cvec[i] = sum_jm effweight[jm->i] * bias[jm]  (bias folded constant)
// effM covers jm<768; tail jm in [768,784) read directly from w/conn/ex.
// ---------------------------------------------------------------------------
__global__ __launch_bounds__(64) void prep_cvec(
    const unsigned short* __restrict__ effM, const float* __restrict__ w,
    const int* __restrict__ conn, const int* __restrict__ ex,
    const float* __restrict__ bias, float* __restrict__ cvec) {
  const int i = blockIdx.x;
  const int l = threadIdx.x;
  float s = 0.f;
  for (int jm = l; jm < MROW; jm += 64)
    s += bf2f(effM[(size_t)i * MROW + jm]) * bias[jm];
  {
    int jm = MROW + l;                 // 768..831; valid only 768..783
    if (jm < NMID && jm < i) {
      size_t idx = (size_t)(INPUT_DIM + jm) * NMID + i;
      s += w[idx] * (float)conn[idx] * (float)ex[jm] * bias[jm];
    }
  }
  for (int off = 32; off; off >>= 1) s += __shfl_down(s, off, 64);
  if (l == 0) cvec[i] = s;
}

// ---------------------------------------------------------------------------
// Prep 3: wpk[b][k][c] (bf16): k<c -> w[256+16b+k][16b+c]*conn*ex[16b+k]
//                              k==c -> cvec[16b+k]; k>c -> 0
// ---------------------------------------------------------------------------
__global__ __launch_bounds__(256) void prep_wpack(
    const float* __restrict__ w, const int* __restrict__ conn,
    const int* __restrict__ ex, const float* __restrict__ cvec,
    unsigned short* __restrict__ wpk) {
  const int b = blockIdx.x;
  const int k = threadIdx.x >> 4;
  const int c = threadIdx.x & 15;
  const int src = KB * b + k;
  const int dst = KB * b + c;
  float v = 0.f;
  if (k < c) {
    size_t idx = (size_t)(INPUT_DIM + src) * NMID + dst;
    v = w[idx] * (float)conn[idx] * (float)ex[src];
  } else if (k == c) {
    v = cvec[src];
  }
  wpk[b * 256 + k * 16 + c] = (unsigned short)f2bf(v);
}

// ---------------------------------------------------------------------------
// P-GEMM: Pt[node][batch_local] = sum_k effX[node][k] * x[batch][k], bf16 out.
// wg = 448 thr (7 waves), wave = 16 nodes x 256 batch (16 sub-tiles), K=256.
// ---------------------------------------------------------------------------
__global__ __launch_bounds__(448) void pgemm(
    const float* __restrict__ x, const unsigned short* __restrict__ effX,
    unsigned short* __restrict__ Pt, int slab_off, int slabsz) {
  const int tid = threadIdx.x;
  const int l   = tid & 63;
  const int wv  = tid >> 6;          // 0..6
  const int g   = l >> 4;
  const int r16 = l & 15;
  const int node0 = blockIdx.y * 112 + wv * 16;
  const int bb0   = blockIdx.x * 256;          // batch base (slab-local)

  uint4 afr[8];
  #pragma unroll
  for (int c = 0; c < 8; ++c)
    afr[c] = *(const uint4*)(effX + (size_t)(node0 + r16) * INPUT_DIM +
                             32 * c + 8 * g);

  #pragma unroll 2
  for (int s = 0; s < 16; ++s) {
    const int brow = bb0 + s * 16 + r16;       // slab-local batch row
    const float* xp = x + (size_t)(slab_off + brow) * INPUT_DIM + 8 * g;
    f32x4 acc = {0.f, 0.f, 0.f, 0.f};
    #pragma unroll
    for (int c = 0; c < 8; ++c) {
      f32x8v xv;
      *(float4*)&xv       = *(const float4*)(xp + 32 * c);
      *((float4*)&xv + 1) = *(const float4*)(xp + 32 * c + 4);
      bf16x8 bv = __builtin_convertvector(xv, bf16x8);
      acc = __builtin_amdgcn_mfma_f32_16x16x32_bf16(
          __builtin_bit_cast(bf16x8, afr[c]), bv, acc, 0, 0, 0);
    }
    // C[m=node0+4g+i][n=brow]
    #pragma unroll
    for (int i = 0; i < 4; ++i)
      Pt[(size_t)(node0 + 4 * g + i) * slabsz + brow] =
          (unsigned short)f2bf(acc[i]);
  }
}

// ---------------------------------------------------------------------------
// Main sequential kernel. Wave = 16 batch rows, middle state in regs
// (uint4 sfrag[24], MFMA-A fragment layout). Per block:
//   C-init from Pt (x contribution) -> MFMA over prior middle chunks
//   (B from phase-organized, XOR-swizzled LDS; global_load_lds staged,
//    double-buffered) -> 2-round LDS transpose -> in-reg triangular solve
//   (bf16 wtri rows from LDS, broadcast reads) -> pack into owning frag reg.
// One barrier per block. 3 wg/CU target (LDS 52352 B, <=170 VGPR).
// ---------------------------------------------------------------------------
__global__ __launch_bounds__(256, 3) void net_main(
    const unsigned short* __restrict__ Pt,
    const unsigned short* __restrict__ effM,
    const unsigned short* __restrict__ wpk,
    const float* __restrict__ bias, const int* __restrict__ ex,
    float* __restrict__ out, int slab_off, int slabsz) {
  __shared__ __align__(16) unsigned short Bs[2][3][16][256];  // 49152 B
  __shared__ __align__(16) unsigned short wtriL[2][256];      //  1024 B
  __shared__ float scr8S[4][8 * 17];                          //  2176 B

  const int tid = threadIdx.x;
  const int l   = tid & 63;
  const int wv  = tid >> 6;
  const int g   = l >> 4;
  const int r16 = l & 15;
  const int rb  = (blockIdx.x * 4 + wv) * 16;   // slab-local batch base
  float* scr8 = scr8S[wv];

  uint4 sfrag[NMCH];
  #pragma unroll
  for (int c = 0; c < NMCH; ++c) {
    uint4 z; z.x = z.y = z.z = z.w = 0u;
    sfrag[c] = z;
  }

  // Stage B rows of block t into buffer nb. Phase-organized LDS
  // [3][16][512B]; dest linear (global_load_lds), source pre-swizzled:
  // phys col16 slot holds logical col16 ^ (row&7)  (T2/m173 pattern).
#define STAGE_B(nb, t)                                                        \
  {                                                                           \
    _Pragma("unroll")                                                         \
    for (int q_ = 0; q_ < 2; ++q_) {                                          \
      const int rp_ = wv + 4 * q_;                                            \
      const int r_  = 2 * rp_ + (l >> 5);                                     \
      const int cl_ = (l & 31) ^ (r_ & 7);                                    \
      const unsigned short* gs_ =                                             \
          effM + (size_t)(16 * (t) + r_) * MROW + cl_ * 8;                    \
      GLL16(gs_, &Bs[nb][0][2 * rp_][0]);                                     \
      if ((t) >= 17) GLL16(gs_ + 256, &Bs[nb][1][2 * rp_][0]);                \
      if ((t) >= 33) GLL16(gs_ + 512, &Bs[nb][2][2 * rp_][0]);                \
    }                                                                         \
  }

  // prologue: wtri for block 0
  if (wv == 0) {
    uint2 t0 = *(const uint2*)(wpk + l * 4);
    *(uint2*)&wtriL[0][l * 4] = t0;
  }
  __syncthreads();

  for (int b = 0; b < NBLK; ++b) {
    const int cur = b & 1;

    if (b + 1 < NBLK) {
      STAGE_B(cur ^ 1, b + 1);
      if (wv == 0) {
        uint2 tw = *(const uint2*)(wpk + (b + 1) * 256 + l * 4);
        *(uint2*)&wtriL[cur ^ 1][l * 4] = tw;
      }
    }

    // ---- C-init from Pt: lane reg i <- Pt[16b+r16][rb+4g+i] ----
    uint2 praw = *(const uint2*)(Pt + (size_t)(KB * b + r16) * slabsz +
                                 rb + 4 * g);
    f32x4 ac0, ac1 = {0.f, 0.f, 0.f, 0.f}, ac2 = ac1, ac3 = ac1;
    ac0[0] = bflo(praw.x);
    ac0[1] = bfhi(praw.x);
    ac0[2] = bflo(praw.y);
    ac0[3] = bfhi(praw.y);

    // ---- GEMM over prior middle chunks (phase-guarded straight lines) ----
#define CHUNK(c)                                                              \
  {                                                                           \
    const int pp_ = (c) >> 3, cc_ = (c) & 7;                                  \
    uint4 braw = *(const uint4*)&Bs[cur][pp_][r16]                            \
        [((cc_ * 4 + g) ^ (r16 & 7)) * 8];                                    \
    f32x4& a_ = ((c) & 3) == 0 ? ac0 : ((c) & 3) == 1 ? ac1                   \
               : ((c) & 3) == 2 ? ac2 : ac3;                                  \
    a_ = __builtin_amdgcn_mfma_f32_16x16x32_bf16(                             \
        __builtin_bit_cast(bf16x8, sfrag[(c)]),                               \
        __builtin_bit_cast(bf16x8, braw), a_, 0, 0, 0);                       \
  }
    if (b >= 1) {
      CHUNK(0) CHUNK(1) CHUNK(2) CHUNK(3)
      CHUNK(4) CHUNK(5) CHUNK(6) CHUNK(7)
    }
    if (b >= 17) {
      CHUNK(8) CHUNK(9) CHUNK(10) CHUNK(11)
      CHUNK(12) CHUNK(13) CHUNK(14) CHUNK(15)
    }
    if (b >= 33) {
      CHUNK(16) CHUNK(17) CHUNK(18) CHUNK(19)
      CHUNK(20) CHUNK(21) CHUNK(22) CHUNK(23)
    }
#undef CHUNK
    f32x4 accsum = (ac0 + ac1) + (ac2 + ac3);

    // ---- transpose, two 8-row rounds through scr8 (per-wave) ----
    float acc_t[16];
    if (g < 2) {
      #pragma unroll
      for (int i = 0; i < 4; ++i)
        scr8[(4 * g + i) * 17 + r16] = accsum[i];
    }
    if (r16 < 8) {
      #pragma unroll
      for (int c = 0; c < 16; ++c) acc_t[c] = scr8[r16 * 17 + c];
    }
    if (g >= 2) {
      #pragma unroll
      for (int i = 0; i < 4; ++i)
        scr8[(4 * (g - 2) + i) * 17 + r16] = accsum[i];
    }
    if (r16 >= 8) {
      #pragma unroll
      for (int c = 0; c < 16; ++c) acc_t[c] = scr8[(r16 - 8) * 17 + c];
    }

    // ---- triangular solve: bf16 wtri rows, uniform-addr broadcast reads ----
    const unsigned short* wt = wtriL[cur];
    #pragma unroll
    for (int k = 0; k < 16; ++k) {
      const uint4 w0 = *(const uint4*)&wt[k * 16];
      const uint4 w1 = *(const uint4*)&wt[k * 16 + 8];
      const unsigned int wd[8] = {w0.x, w0.y, w0.z, w0.w,
                                  w1.x, w1.y, w1.z, w1.w};
      float xk = acc_t[k] + ((k & 1) ? bfhi(wd[k >> 1]) : bflo(wd[k >> 1]));
      float s  = __builtin_amdgcn_rcpf(
          1.f + __builtin_amdgcn_exp2f(xk * -1.44269504088896341f));
      acc_t[k] = s;
      #pragma unroll
      for (int c = k + 1; c < 16; ++c) {
        float wc = (c & 1) ? bfhi(wd[c >> 1]) : bflo(wd[c >> 1]);
        acc_t[c] = __builtin_fmaf(s, wc, acc_t[c]);
      }
    }

    if (b == NBLK - 1) {
      const size_t orow = (size_t)(slab_off + rb + r16) * OUT_DIM;
      #pragma unroll
      for (int i = 0; i < 4; ++i) {
        int oc = 4 * g + i;
        int mi = NMID - OUT_DIM + oc;
        out[orow + oc] = (acc_t[oc] + bias[mi]) * (float)ex[mi];
      }
    } else {
      // pack the 16 new values into the owning middle-chunk register
      const int cm = b >> 1;
      const int vb = 8 * (g & 1);
      uint4 packed;
      packed.x = f2bf(acc_t[vb + 0]) | (f2bf(acc_t[vb + 1]) << 16);
      packed.y = f2bf(acc_t[vb + 2]) | (f2bf(acc_t[vb + 3]) << 16);
      packed.z = f2bf(acc_t[vb + 4]) | (f2bf(acc_t[vb + 5]) << 16);
      packed.w = f2bf(acc_t[vb + 6]) | (f2bf(acc_t[vb + 7]) << 16);
      const bool part = ((g >> 1) == (b & 1));
      #pragma unroll
      for (int c = 0; c < NMCH; ++c) {
        if (c == cm) {                 // wave-uniform guard
          if (part) sfrag[c] = packed;
        }
      }
    }

    __syncthreads();   // publish staged B/wtri; prior LDS reads done
  }
#undef STAGE_B
}

// ---------------------------------------------------------------------------
extern "C" void kernel_launch(void* const* d_in, const int* in_sizes, int n_in,
                              void* d_out, int out_size, void* d_ws, size_t ws_size,
                              hipStream_t stream) {
  const float* x      = (const float*)d_in[0];
  const float* weight = (const float*)d_in[1];
  const float* bias   = (const float*)d_in[2];
  const int*   conn   = (const int*)d_in[3];
  const int*   ex     = (const int*)d_in[4];

  char* ws = (char*)d_ws;
  size_t off = 0;
  unsigned short* effX = (unsigned short*)(ws + off); off += (size_t)NMID * INPUT_DIM * 2;
  unsigned short* effM = (unsigned short*)(ws + off); off += (size_t)NMID * MROW * 2;
  float*          cvec = (float*)(ws + off);          off += (size_t)NMID * 4;
  unsigned short* wpk  = (unsigned short*)(ws + off); off += (size_t)NBLK * 256 * 2;
  off = (off + 255) & ~(size_t)255;
  const size_t fixed = off;

  // Pt slab sizing: smallest power-of-two slab count that fits ws.
  int nslabs = 1;
  while (nslabs < 16 &&
         fixed + (size_t)NMID * (BATCH / nslabs) * 2 > ws_size)
    nslabs <<= 1;
  const int slabsz = BATCH / nslabs;
  unsigned short* Pt = (unsigned short*)(ws + fixed);

  prep_efft<<<dim3(16, 13), 256, 0, stream>>>(weight, conn, ex, effX, effM);
  prep_cvec<<<dim3(NMID), 64, 0, stream>>>(effM, weight, conn, ex, bias, cvec);
  prep_wpack<<<dim3(NBLK), 256, 0, stream>>>(weight, conn, ex, cvec, wpk);

  for (int s = 0; s < nslabs; ++s) {
    pgemm<<<dim3(slabsz / 256, 7), 448, 0, stream>>>(
        x, effX, Pt, s * slabsz, slabsz);
    net_main<<<dim3(slabsz / 64), 256, 0, stream>>>(
        Pt, effM, wpk, bias, ex, (float*)d_out, s * slabsz, slabsz);
  }
}

// Round 6
// 409.405 us; speedup vs baseline: 2.5679x; 2.5679x over previous
//
#include <hip/hip_runtime.h>
#include <cstdint>
#include <cstddef>

#define INPUT_DIM 256
#define OUT_DIM   16
#define NMID      784     // middle nodes
#define NNODE     1040
#define MROW      768     // effM row length (middle cols; cols >=768 are in-block only)
#define KB        16      // node block size
#define NBLK      49      // 784 / 16
#define NMCH      24      // middle-state chunks of 32 k-elems (768/32)
#define BATCH     32768
#define UNITW     520     // ushorts per 2-row LDS unit (1040 B; 260 words ≡ 4 mod 32)

typedef float f32x4 __attribute__((ext_vector_type(4)));
typedef float f32x8v __attribute__((ext_vector_type(8)));
typedef __bf16 bf16x8 __attribute__((ext_vector_type(8)));

#define GLL16(gp, lp)                                                        \
  __builtin_amdgcn_global_load_lds(                                          \
      (const __attribute__((address_space(1))) unsigned int*)(gp),           \
      (__attribute__((address_space(3))) unsigned int*)(lp), 16, 0, 0)

static __device__ __forceinline__ unsigned int f2bf(float f) {
  unsigned int u = __builtin_bit_cast(unsigned int, f);
  u += 0x7fffu + ((u >> 16) & 1u);   // round-to-nearest-even
  return u >> 16;
}
static __device__ __forceinline__ float bf2f(unsigned short h) {
  unsigned int u = ((unsigned int)h) << 16;
  return __builtin_bit_cast(float, u);
}
static __device__ __forceinline__ float bflo(unsigned int w) {
  return __builtin_bit_cast(float, w << 16);
}
static __device__ __forceinline__ float bfhi(unsigned int w) {
  return __builtin_bit_cast(float, w & 0xffff0000u);
}

// ---------------------------------------------------------------------------
// Prep 1: split masked weights into
//   effX[i][k]  = w[k][i]*conn[k][i]              (k<256, always causal), bf16
//   effM[i][jm] = w[256+jm][i]*conn*ex[jm]*(jm<i) (jm<768; jm>=768 is in-block
//                 for block 48 and handled by wtri), bf16
// ---------------------------------------------------------------------------
__global__ __launch_bounds__(256) void prep_efft(
    const float* __restrict__ w, const int* __restrict__ conn,
    const int* __restrict__ ex, unsigned short* __restrict__ effX,
    unsigned short* __restrict__ effM) {
  __shared__ unsigned short tile[64][66];
  const int j0 = blockIdx.x * 64;
  const int i0 = blockIdx.y * 64;
  const int tx = threadIdx.x & 63;   // i offset
  const int ty = threadIdx.x >> 6;   // j sub-row
  const int i  = i0 + tx;
  for (int t = 0; t < 16; ++t) {
    int j = j0 + t * 4 + ty;
    float v = 0.f;
    if (j < NNODE && i < NMID && j < INPUT_DIM + i) {
      float e = (j >= INPUT_DIM) ? (float)ex[j - INPUT_DIM] : 1.f;
      v = w[(size_t)j * NMID + i] * (float)conn[(size_t)j * NMID + i] * e;
    }
    tile[t * 4 + ty][tx] = (unsigned short)f2bf(v);
  }
  __syncthreads();
  const int i_loc = threadIdx.x >> 2;
  const int jq    = threadIdx.x & 3;
  const int iw    = i0 + i_loc;
  const int jbase = j0 + jq * 16;
  if (iw < NMID) {
    if (jbase + 16 <= INPUT_DIM) {
      #pragma unroll
      for (int c = 0; c < 16; ++c)
        effX[(size_t)iw * INPUT_DIM + jbase + c] = tile[jq * 16 + c][i_loc];
    } else if (jbase >= INPUT_DIM && (jbase - INPUT_DIM + 16) <= MROW) {
      #pragma unroll
      for (int c = 0; c < 16; ++c)
        effM[(size_t)iw * MROW + (jbase - INPUT_DIM) + c] =
            tile[jq * 16 + c][i_loc];
    }
  }
}

// ---------------------------------------------------------------------------
// Prep 2: cvec[i] = sum_jm effweight[jm->i] * bias[jm]  (bias folded constant)
// effM covers jm<768; tail jm in [768,784) read directly from w/conn/ex.
// ---------------------------------------------------------------------------
__global__ __launch_bounds__(64) void prep_cvec(
    const unsigned short* __restrict__ effM, const float* __restrict__ w,
    const int* __restrict__ conn, const int* __restrict__ ex,
    const float* __restrict__ bias, float* __restrict__ cvec) {
  const int i = blockIdx.x;
  const int l = threadIdx.x;
  float s = 0.f;
  for (int jm = l; jm < MROW; jm += 64)
    s += bf2f(effM[(size_t)i * MROW + jm]) * bias[jm];
  {
    int jm = MROW + l;                 // 768..831; valid only 768..783
    if (jm < NMID && jm < i) {
      size_t idx = (size_t)(INPUT_DIM + jm) * NMID + i;
      s += w[idx] * (float)conn[idx] * (float)ex[jm] * bias[jm];
    }
  }
  for (int off = 32; off; off >>= 1) s += __shfl_down(s, off, 64);
  if (l == 0) cvec[i] = s;
}

// ---------------------------------------------------------------------------
// Prep 3: wpk[b][k][c] (bf16): k<c -> w[256+16b+k][16b+c]*conn*ex[16b+k]
//                              k==c -> cvec[16b+k]; k>c -> 0
// ---------------------------------------------------------------------------
__global__ __launch_bounds__(256) void prep_wpack(
    const float* __restrict__ w, const int* __restrict__ conn,
    const int* __restrict__ ex, const float* __restrict__ cvec,
    unsigned short* __restrict__ wpk) {
  const int b = blockIdx.x;
  const int k = threadIdx.x >> 4;
  const int c = threadIdx.x & 15;
  const int src = KB * b + k;
  const int dst = KB * b + c;
  float v = 0.f;
  if (k < c) {
    size_t idx = (size_t)(INPUT_DIM + src) * NMID + dst;
    v = w[idx] * (float)conn[idx] * (float)ex[src];
  } else if (k == c) {
    v = cvec[src];
  }
  wpk[b * 256 + k * 16 + c] = (unsigned short)f2bf(v);
}

// ---------------------------------------------------------------------------
// P-GEMM: Pt[node][batch_local] = sum_k effX[node][k] * x[batch][k], bf16 out.
// wg = 448 thr (7 waves), wave = 16 nodes x 256 batch (16 sub-tiles), K=256.
// ---------------------------------------------------------------------------
__global__ __launch_bounds__(448) void pgemm(
    const float* __restrict__ x, const unsigned short* __restrict__ effX,
    unsigned short* __restrict__ Pt, int slab_off, int slabsz) {
  const int tid = threadIdx.x;
  const int l   = tid & 63;
  const int wv  = tid >> 6;          // 0..6
  const int g   = l >> 4;
  const int r16 = l & 15;
  const int node0 = blockIdx.y * 112 + wv * 16;
  const int bb0   = blockIdx.x * 256;          // batch base (slab-local)

  uint4 afr[8];
  #pragma unroll
  for (int c = 0; c < 8; ++c)
    afr[c] = *(const uint4*)(effX + (size_t)(node0 + r16) * INPUT_DIM +
                             32 * c + 8 * g);

  #pragma unroll 2
  for (int s = 0; s < 16; ++s) {
    const int brow = bb0 + s * 16 + r16;       // slab-local batch row
    const float* xp = x + (size_t)(slab_off + brow) * INPUT_DIM + 8 * g;
    f32x4 acc = {0.f, 0.f, 0.f, 0.f};
    #pragma unroll
    for (int c = 0; c < 8; ++c) {
      f32x8v xv;
      *(float4*)&xv       = *(const float4*)(xp + 32 * c);
      *((float4*)&xv + 1) = *(const float4*)(xp + 32 * c + 4);
      bf16x8 bv = __builtin_convertvector(xv, bf16x8);
      acc = __builtin_amdgcn_mfma_f32_16x16x32_bf16(
          __builtin_bit_cast(bf16x8, afr[c]), bv, acc, 0, 0, 0);
    }
    // C[m=node0+4g+i][n=brow]
    #pragma unroll
    for (int i = 0; i < 4; ++i)
      Pt[(size_t)(node0 + 4 * g + i) * slabsz + brow] =
          (unsigned short)f2bf(acc[i]);
  }
}

// ---------------------------------------------------------------------------
// Main sequential kernel. Wave = 16 batch rows, middle state in regs
// (uint4 sfrag[24], MFMA-A fragment layout). Per block:
//   MFMA over prior middle chunks (B from phase-organized, XOR-swizzled,
//   unit-padded LDS; global_load_lds staged, double-buffered) -> add Pt
//   (x contribution, latency hidden under GEMM) -> LDS transpose ->
//   in-reg triangular solve (bf16 wtri from LDS, broadcast reads) ->
//   pack into owning fragment reg. One barrier per block. 2 wg/CU, no spill.
// ---------------------------------------------------------------------------
__global__ __launch_bounds__(256, 2) void net_main(
    const unsigned short* __restrict__ Pt,
    const unsigned short* __restrict__ effM,
    const unsigned short* __restrict__ wpk,
    const float* __restrict__ bias, const int* __restrict__ ex,
    float* __restrict__ out, int slab_off, int slabsz) {
  __shared__ __align__(16) unsigned short Bs[2][3][8][UNITW];  // 49920 B
  __shared__ __align__(16) unsigned short wtriL[2][256];       //  1024 B
  __shared__ float scrS[4][320];                               //  5120 B

  const int tid = threadIdx.x;
  const int l   = tid & 63;
  const int wv  = tid >> 6;
  const int g   = l >> 4;
  const int r16 = l & 15;
  const int rb  = (blockIdx.x * 4 + wv) * 16;   // slab-local batch base
  float* myscr = scrS[wv];

  uint4 sfrag[NMCH];
  #pragma unroll
  for (int c = 0; c < NMCH; ++c) {
    uint4 z; z.x = z.y = z.z = z.w = 0u;
    sfrag[c] = z;
  }

  // Stage B rows of block t into buffer nb. Phase-organized LDS
  // [3][unit=2 rows][1040 B]; dest linear per unit (global_load_lds),
  // source pre-swizzled: phys 16B-slot (l&31) holds logical slot
  // (l&31)^(row&7)  (T2/m173 pattern; read applies the same XOR).
#define STAGE_B(nb, t)                                                        \
  {                                                                           \
    _Pragma("unroll")                                                         \
    for (int q_ = 0; q_ < 2; ++q_) {                                          \
      const int rp_ = wv + 4 * q_;           /* unit 0..7 */                  \
      const int r_  = 2 * rp_ + (l >> 5);    /* B-row 0..15 */                \
      const int cl_ = (l & 31) ^ (r_ & 7);                                    \
      const unsigned short* gs_ =                                             \
          effM + (size_t)(16 * (t) + r_) * MROW + cl_ * 8;                    \
      GLL16(gs_, &Bs[nb][0][rp_][0]);                                         \
      if ((t) >= 17) GLL16(gs_ + 256, &Bs[nb][1][rp_][0]);                    \
      if ((t) >= 33) GLL16(gs_ + 512, &Bs[nb][2][rp_][0]);                    \
    }                                                                         \
  }

  // prologue: wtri for block 0 (block 0 has no B-chunks)
  if (wv == 0) {
    uint2 t0 = *(const uint2*)(wpk + l * 4);
    *(uint2*)&wtriL[0][l * 4] = t0;
  }
  __syncthreads();

  for (int b = 0; b < NBLK; ++b) {
    const int cur = b & 1;

    if (b + 1 < NBLK) {
      STAGE_B(cur ^ 1, b + 1);
      if (wv == 0) {
        uint2 tw = *(const uint2*)(wpk + (b + 1) * 256 + l * 4);
        *(uint2*)&wtriL[cur ^ 1][l * 4] = tw;
      }
    }

    // Pt (x contribution): issued here, consumed after the GEMM.
    uint2 praw = *(const uint2*)(Pt + (size_t)(KB * b + r16) * slabsz +
                                 rb + 4 * g);

    // ---- GEMM over prior middle chunks (phase-guarded straight lines) ----
    f32x4 ac0 = {0.f, 0.f, 0.f, 0.f}, ac1 = ac0, ac2 = ac0, ac3 = ac0;
#define CHUNK(c)                                                              \
  {                                                                           \
    const int pp_ = (c) >> 3, cc_ = (c) & 7;                                  \
    uint4 braw = *(const uint4*)&Bs[cur][pp_][r16 >> 1]                       \
        [(r16 & 1) * 256 + (((cc_ * 4 + g) ^ (r16 & 7)) * 8)];                \
    f32x4& a_ = ((c) & 3) == 0 ? ac0 : ((c) & 3) == 1 ? ac1                   \
               : ((c) & 3) == 2 ? ac2 : ac3;                                  \
    a_ = __builtin_amdgcn_mfma_f32_16x16x32_bf16(                             \
        __builtin_bit_cast(bf16x8, sfrag[(c)]),                               \
        __builtin_bit_cast(bf16x8, braw), a_, 0, 0, 0);                       \
  }
    if (b >= 1) {
      CHUNK(0) CHUNK(1) CHUNK(2) CHUNK(3)
      CHUNK(4) CHUNK(5) CHUNK(6) CHUNK(7)
    }
    if (b >= 17) {
      CHUNK(8) CHUNK(9) CHUNK(10) CHUNK(11)
      CHUNK(12) CHUNK(13) CHUNK(14) CHUNK(15)
    }
    if (b >= 33) {
      CHUNK(16) CHUNK(17) CHUNK(18) CHUNK(19)
      CHUNK(20) CHUNK(21) CHUNK(22) CHUNK(23)
    }
#undef CHUNK
    f32x4 accsum = (ac0 + ac1) + (ac2 + ac3);
    accsum[0] += bflo(praw.x);
    accsum[1] += bfhi(praw.x);
    accsum[2] += bflo(praw.y);
    accsum[3] += bfhi(praw.y);

    // ---- transpose via per-wave LDS scratch (C-layout -> row-per-lane) ----
    #pragma unroll
    for (int i = 0; i < 4; ++i)
      myscr[(4 * g + i) * 20 + r16] = accsum[i];
    float acc_t[16];
    #pragma unroll
    for (int c = 0; c < 16; ++c)
      acc_t[c] = myscr[r16 * 20 + c];

    // ---- triangular solve: bf16 wtri rows, uniform-addr broadcast reads ----
    const unsigned short* wt = wtriL[cur];
    #pragma unroll
    for (int k = 0; k < 16; ++k) {
      const uint4 w0 = *(const uint4*)&wt[k * 16];
      const uint4 w1 = *(const uint4*)&wt[k * 16 + 8];
      const unsigned int wd[8] = {w0.x, w0.y, w0.z, w0.w,
                                  w1.x, w1.y, w1.z, w1.w};
      float xk = acc_t[k] + ((k & 1) ? bfhi(wd[k >> 1]) : bflo(wd[k >> 1]));
      float s  = __builtin_amdgcn_rcpf(
          1.f + __builtin_amdgcn_exp2f(xk * -1.44269504088896341f));
      acc_t[k] = s;
      #pragma unroll
      for (int c = k + 1; c < 16; ++c) {
        float wc = (c & 1) ? bfhi(wd[c >> 1]) : bflo(wd[c >> 1]);
        acc_t[c] = __builtin_fmaf(s, wc, acc_t[c]);
      }
    }

    if (b == NBLK - 1) {
      const size_t orow = (size_t)(slab_off + rb + r16) * OUT_DIM;
      #pragma unroll
      for (int i = 0; i < 4; ++i) {
        int oc = 4 * g + i;
        int mi = NMID - OUT_DIM + oc;
        out[orow + oc] = (acc_t[oc] + bias[mi]) * (float)ex[mi];
      }
    } else {
      // pack the 16 new values into the owning middle-chunk register
      const int cm = b >> 1;
      const int vb = 8 * (g & 1);
      uint4 packed;
      packed.x = f2bf(acc_t[vb + 0]) | (f2bf(acc_t[vb + 1]) << 16);
      packed.y = f2bf(acc_t[vb + 2]) | (f2bf(acc_t[vb + 3]) << 16);
      packed.z = f2bf(acc_t[vb + 4]) | (f2bf(acc_t[vb + 5]) << 16);
      packed.w = f2bf(acc_t[vb + 6]) | (f2bf(acc_t[vb + 7]) << 16);
      const bool part = ((g >> 1) == (b & 1));
      #pragma unroll
      for (int c = 0; c < NMCH; ++c) {
        if (c == cm) {                 // wave-uniform guard
          if (part) sfrag[c] = packed;
        }
      }
    }

    __syncthreads();   // publish staged B/wtri; prior LDS reads done
  }
#undef STAGE_B
}

// ---------------------------------------------------------------------------
extern "C" void kernel_launch(void* const* d_in, const int* in_sizes, int n_in,
                              void* d_out, int out_size, void* d_ws, size_t ws_size,
                              hipStream_t stream) {
  const float* x      = (const float*)d_in[0];
  const float* weight = (const float*)d_in[1];
  const float* bias   = (const float*)d_in[2];
  const int*   conn   = (const int*)d_in[3];
  const int*   ex     = (const int*)d_in[4];

  char* ws = (char*)d_ws;
  size_t off = 0;
  unsigned short* effX = (unsigned short*)(ws + off); off += (size_t)NMID * INPUT_DIM * 2;
  unsigned short* effM = (unsigned short*)(ws + off); off += (size_t)NMID * MROW * 2;
  float*          cvec = (float*)(ws + off);          off += (size_t)NMID * 4;
  unsigned short* wpk  = (unsigned short*)(ws + off); off += (size_t)NBLK * 256 * 2;
  off = (off + 255) & ~(size_t)255;
  const size_t fixed = off;

  // Pt slab sizing: smallest power-of-two slab count that fits ws.
  int nslabs = 1;
  while (nslabs < 16 &&
         fixed + (size_t)NMID * (BATCH / nslabs) * 2 > ws_size)
    nslabs <<= 1;
  const int slabsz = BATCH / nslabs;
  unsigned short* Pt = (unsigned short*)(ws + fixed);

  prep_efft<<<dim3(16, 13), 256, 0, stream>>>(weight, conn, ex, effX, effM);
  prep_cvec<<<dim3(NMID), 64, 0, stream>>>(effM, weight, conn, ex, bias, cvec);
  prep_wpack<<<dim3(NBLK), 256, 0, stream>>>(weight, conn, ex, cvec, wpk);

  for (int s = 0; s < nslabs; ++s) {
    pgemm<<<dim3(slabsz / 256, 7), 448, 0, stream>>>(
        x, effX, Pt, s * slabsz, slabsz);
    net_main<<<dim3(slabsz / 64), 256, 0, stream>>>(
        Pt, effM, wpk, bias, ex, (float*)d_out, s * slabsz, slabsz);
  }
}

// Round 7
// 239.682 us; speedup vs baseline: 4.3862x; 1.7081x over previous
//
#include <hip/hip_runtime.h>
#include <cstdint>
#include <cstddef>

#define INPUT_DIM 256
#define OUT_DIM   16
#define NMID      784     // middle nodes
#define NNODE     1040
#define MROW      768     // effM row length (middle cols; cols >=768 are in-block only)
#define KB        16      // node block size
#define NBLK      49      // 784 / 16
#define NMCH      24      // middle-state chunks of 32 k-elems (768/32)
#define BATCH     32768
#define UNITW     520     // ushorts per 2-row LDS unit (1040 B; 260 words ≡ 4 mod 32)
#define XROW      264     // pgemm LDS x row stride (528 B; 132 words ≡ 4 mod 32)

typedef float f32x4 __attribute__((ext_vector_type(4)));
typedef __bf16 bf16x8 __attribute__((ext_vector_type(8)));

#define GLL16(gp, lp)                                                        \
  __builtin_amdgcn_global_load_lds(                                          \
      (const __attribute__((address_space(1))) unsigned int*)(gp),           \
      (__attribute__((address_space(3))) unsigned int*)(lp), 16, 0, 0)

static __device__ __forceinline__ unsigned int f2bf(float f) {
  unsigned int u = __builtin_bit_cast(unsigned int, f);
  u += 0x7fffu + ((u >> 16) & 1u);   // round-to-nearest-even
  return u >> 16;
}
static __device__ __forceinline__ float bf2f(unsigned short h) {
  unsigned int u = ((unsigned int)h) << 16;
  return __builtin_bit_cast(float, u);
}
static __device__ __forceinline__ float bflo(unsigned int w) {
  return __builtin_bit_cast(float, w << 16);
}
static __device__ __forceinline__ float bfhi(unsigned int w) {
  return __builtin_bit_cast(float, w & 0xffff0000u);
}

// ---------------------------------------------------------------------------
// Prep 1: split masked weights into
//   effX[i][k]  = w[k][i]*conn[k][i]              (k<256, always causal), bf16
//   effM[i][jm] = w[256+jm][i]*conn*ex[jm]*(jm<i) (jm<768; jm>=768 is in-block
//                 for block 48 and handled by wtri), bf16
// ---------------------------------------------------------------------------
__global__ __launch_bounds__(256) void prep_efft(
    const float* __restrict__ w, const int* __restrict__ conn,
    const int* __restrict__ ex, unsigned short* __restrict__ effX,
    unsigned short* __restrict__ effM) {
  __shared__ unsigned short tile[64][66];
  const int j0 = blockIdx.x * 64;
  const int i0 = blockIdx.y * 64;
  const int tx = threadIdx.x & 63;   // i offset
  const int ty = threadIdx.x >> 6;   // j sub-row
  const int i  = i0 + tx;
  for (int t = 0; t < 16; ++t) {
    int j = j0 + t * 4 + ty;
    float v = 0.f;
    if (j < NNODE && i < NMID && j < INPUT_DIM + i) {
      float e = (j >= INPUT_DIM) ? (float)ex[j - INPUT_DIM] : 1.f;
      v = w[(size_t)j * NMID + i] * (float)conn[(size_t)j * NMID + i] * e;
    }
    tile[t * 4 + ty][tx] = (unsigned short)f2bf(v);
  }
  __syncthreads();
  const int i_loc = threadIdx.x >> 2;
  const int jq    = threadIdx.x & 3;
  const int iw    = i0 + i_loc;
  const int jbase = j0 + jq * 16;
  if (iw < NMID) {
    if (jbase + 16 <= INPUT_DIM) {
      #pragma unroll
      for (int c = 0; c < 16; ++c)
        effX[(size_t)iw * INPUT_DIM + jbase + c] = tile[jq * 16 + c][i_loc];
    } else if (jbase >= INPUT_DIM && (jbase - INPUT_DIM + 16) <= MROW) {
      #pragma unroll
      for (int c = 0; c < 16; ++c)
        effM[(size_t)iw * MROW + (jbase - INPUT_DIM) + c] =
            tile[jq * 16 + c][i_loc];
    }
  }
}

// ---------------------------------------------------------------------------
// Prep 2: cvec[i] = sum_jm effweight[jm->i] * bias[jm]  (bias folded constant)
// effM covers jm<768; tail jm in [768,784) read directly from w/conn/ex.
// ---------------------------------------------------------------------------
__global__ __launch_bounds__(64) void prep_cvec(
    const unsigned short* __restrict__ effM, const float* __restrict__ w,
    const int* __restrict__ conn, const int* __restrict__ ex,
    const float* __restrict__ bias, float* __restrict__ cvec) {
  const int i = blockIdx.x;
  const int l = threadIdx.x;
  float s = 0.f;
  for (int jm = l; jm < MROW; jm += 64)
    s += bf2f(effM[(size_t)i * MROW + jm]) * bias[jm];
  {
    int jm = MROW + l;                 // 768..831; valid only 768..783
    if (jm < NMID && jm < i) {
      size_t idx = (size_t)(INPUT_DIM + jm) * NMID + i;
      s += w[idx] * (float)conn[idx] * (float)ex[jm] * bias[jm];
    }
  }
  for (int off = 32; off; off >>= 1) s += __shfl_down(s, off, 64);
  if (l == 0) cvec[i] = s;
}

// ---------------------------------------------------------------------------
// Prep 3: wpk[b][k][c] (bf16): k<c -> w[256+16b+k][16b+c]*conn*ex[16b+k]
//                              k==c -> cvec[16b+k]; k>c -> 0
// ---------------------------------------------------------------------------
__global__ __launch_bounds__(256) void prep_wpack(
    const float* __restrict__ w, const int* __restrict__ conn,
    const int* __restrict__ ex, const float* __restrict__ cvec,
    unsigned short* __restrict__ wpk) {
  const int b = blockIdx.x;
  const int k = threadIdx.x >> 4;
  const int c = threadIdx.x & 15;
  const int src = KB * b + k;
  const int dst = KB * b + c;
  float v = 0.f;
  if (k < c) {
    size_t idx = (size_t)(INPUT_DIM + src) * NMID + dst;
    v = w[idx] * (float)conn[idx] * (float)ex[src];
  } else if (k == c) {
    v = cvec[src];
  }
  wpk[b * 256 + k * 16 + c] = (unsigned short)f2bf(v);
}

// ---------------------------------------------------------------------------
// P-GEMM v2: Pt[node][batch_local] = sum_k effX[node][k] * x[batch][k].
// Block = 256 thr (4 waves), batch tile 64. Stage x[64][256] -> bf16 LDS once
// (one barrier); then waves independently loop node-blocks nb = wv, wv+4,...
// afr in regs (reloaded per nb from L2-resident effX), B-frags from LDS.
// ---------------------------------------------------------------------------
__global__ __launch_bounds__(256)
__attribute__((amdgpu_waves_per_eu(2, 4))) void pgemm(
    const float* __restrict__ x, const unsigned short* __restrict__ effX,
    unsigned short* __restrict__ Pt, int slab_off, int slabsz) {
  __shared__ __align__(16) unsigned short xs[64][XROW];   // 33792 B

  const int tid = threadIdx.x;
  const int l   = tid & 63;
  const int wv  = tid >> 6;
  const int g   = l >> 4;
  const int r16 = l & 15;
  const int bb  = blockIdx.x * 64;          // slab-local batch base

  // ---- stage x tile as bf16 (each thread: one row-quarter, 64 f32) ----
  {
    const int row = tid >> 2;
    const int q   = tid & 3;
    const float* xr = x + (size_t)(slab_off + bb + row) * INPUT_DIM + q * 64;
    unsigned short* xd = &xs[row][q * 64];
    #pragma unroll
    for (int i = 0; i < 16; ++i) {
      float4 v = *(const float4*)(xr + 4 * i);
      uint2 u;
      u.x = f2bf(v.x) | (f2bf(v.y) << 16);
      u.y = f2bf(v.z) | (f2bf(v.w) << 16);
      *(uint2*)(xd + 4 * i) = u;
    }
  }
  __syncthreads();

  // ---- independent per-wave node loop (no further barriers) ----
  for (int nb = wv; nb < NBLK; nb += 4) {
    const unsigned short* ap =
        effX + (size_t)(nb * 16 + r16) * INPUT_DIM + 8 * g;
    uint4 a[8];
    #pragma unroll
    for (int c = 0; c < 8; ++c) a[c] = *(const uint4*)(ap + 32 * c);

    #pragma unroll
    for (int s = 0; s < 4; ++s) {
      f32x4 acc = {0.f, 0.f, 0.f, 0.f};
      #pragma unroll
      for (int c = 0; c < 8; ++c) {
        uint4 braw = *(const uint4*)&xs[s * 16 + r16][32 * c + 8 * g];
        acc = __builtin_amdgcn_mfma_f32_16x16x32_bf16(
            __builtin_bit_cast(bf16x8, a[c]), __builtin_bit_cast(bf16x8, braw),
            acc, 0, 0, 0);
      }
      #pragma unroll
      for (int i = 0; i < 4; ++i)
        Pt[(size_t)(nb * 16 + 4 * g + i) * slabsz + bb + s * 16 + r16] =
            (unsigned short)f2bf(acc[i]);
    }
  }
}

// ---------------------------------------------------------------------------
// Main sequential kernel. Wave = 16 batch rows, middle state in regs
// (uint4 sfrag[24], MFMA-A fragment layout). Per block:
//   MFMA over prior middle chunks (B from phase-organized, XOR-swizzled,
//   unit-padded LDS; global_load_lds staged, double-buffered) -> add Pt ->
//   LDS transpose -> in-reg triangular solve (bf16 wtri broadcast reads) ->
//   pack into owning fragment reg. One barrier per block.
// amdgpu_waves_per_eu(2,2): LDS caps us at 2 wg/CU anyway; give the register
// allocator the full 256-reg budget so it stops spilling to chase occupancy.
// ---------------------------------------------------------------------------
__global__ __launch_bounds__(256)
__attribute__((amdgpu_waves_per_eu(2, 2))) void net_main(
    const unsigned short* __restrict__ Pt,
    const unsigned short* __restrict__ effM,
    const unsigned short* __restrict__ wpk,
    const float* __restrict__ bias, const int* __restrict__ ex,
    float* __restrict__ out, int slab_off, int slabsz) {
  __shared__ __align__(16) unsigned short Bs[2][3][8][UNITW];  // 49920 B
  __shared__ __align__(16) unsigned short wtriL[2][256];       //  1024 B
  __shared__ float scrS[4][320];                               //  5120 B

  const int tid = threadIdx.x;
  const int l   = tid & 63;
  const int wv  = tid >> 6;
  const int g   = l >> 4;
  const int r16 = l & 15;
  const int rb  = (blockIdx.x * 4 + wv) * 16;   // slab-local batch base
  float* myscr = scrS[wv];

  uint4 sfrag[NMCH];
  #pragma unroll
  for (int c = 0; c < NMCH; ++c) {
    uint4 z; z.x = z.y = z.z = z.w = 0u;
    sfrag[c] = z;
  }

  // Stage B rows of block t into buffer nb. Phase-organized LDS
  // [3][unit=2 rows][1040 B]; dest linear per unit (global_load_lds),
  // source pre-swizzled: phys 16B-slot (l&31) holds logical slot
  // (l&31)^(row&7)  (T2/m173 pattern; read applies the same XOR).
#define STAGE_B(nb, t)                                                        \
  {                                                                           \
    _Pragma("unroll")                                                         \
    for (int q_ = 0; q_ < 2; ++q_) {                                          \
      const int rp_ = wv + 4 * q_;           /* unit 0..7 */                  \
      const int r_  = 2 * rp_ + (l >> 5);    /* B-row 0..15 */                \
      const int cl_ = (l & 31) ^ (r_ & 7);                                    \
      const unsigned short* gs_ =                                             \
          effM + (size_t)(16 * (t) + r_) * MROW + cl_ * 8;                    \
      GLL16(gs_, &Bs[nb][0][rp_][0]);                                         \
      if ((t) >= 17) GLL16(gs_ + 256, &Bs[nb][1][rp_][0]);                    \
      if ((t) >= 33) GLL16(gs_ + 512, &Bs[nb][2][rp_][0]);                    \
    }                                                                         \
  }

  // prologue: wtri for block 0 (block 0 has no B-chunks)
  if (wv == 0) {
    uint2 t0 = *(const uint2*)(wpk + l * 4);
    *(uint2*)&wtriL[0][l * 4] = t0;
  }
  __syncthreads();

  for (int b = 0; b < NBLK; ++b) {
    const int cur = b & 1;

    if (b + 1 < NBLK) {
      STAGE_B(cur ^ 1, b + 1);
      if (wv == 0) {
        uint2 tw = *(const uint2*)(wpk + (b + 1) * 256 + l * 4);
        *(uint2*)&wtriL[cur ^ 1][l * 4] = tw;
      }
    }

    // Pt (x contribution): issued here, consumed after the GEMM.
    uint2 praw = *(const uint2*)(Pt + (size_t)(KB * b + r16) * slabsz +
                                 rb + 4 * g);

    // ---- GEMM over prior middle chunks (phase-guarded straight lines) ----
    f32x4 ac0 = {0.f, 0.f, 0.f, 0.f}, ac1 = ac0, ac2 = ac0, ac3 = ac0;
#define CHUNK(c)                                                              \
  {                                                                           \
    const int pp_ = (c) >> 3, cc_ = (c) & 7;                                  \
    uint4 braw = *(const uint4*)&Bs[cur][pp_][r16 >> 1]                       \
        [(r16 & 1) * 256 + (((cc_ * 4 + g) ^ (r16 & 7)) * 8)];                \
    f32x4& a_ = ((c) & 3) == 0 ? ac0 : ((c) & 3) == 1 ? ac1                   \
               : ((c) & 3) == 2 ? ac2 : ac3;                                  \
    a_ = __builtin_amdgcn_mfma_f32_16x16x32_bf16(                             \
        __builtin_bit_cast(bf16x8, sfrag[(c)]),                               \
        __builtin_bit_cast(bf16x8, braw), a_, 0, 0, 0);                       \
  }
    if (b >= 1) {
      CHUNK(0) CHUNK(1) CHUNK(2) CHUNK(3)
      CHUNK(4) CHUNK(5) CHUNK(6) CHUNK(7)
    }
    if (b >= 17) {
      CHUNK(8) CHUNK(9) CHUNK(10) CHUNK(11)
      CHUNK(12) CHUNK(13) CHUNK(14) CHUNK(15)
    }
    if (b >= 33) {
      CHUNK(16) CHUNK(17) CHUNK(18) CHUNK(19)
      CHUNK(20) CHUNK(21) CHUNK(22) CHUNK(23)
    }
#undef CHUNK
    f32x4 accsum = (ac0 + ac1) + (ac2 + ac3);
    accsum[0] += bflo(praw.x);
    accsum[1] += bfhi(praw.x);
    accsum[2] += bflo(praw.y);
    accsum[3] += bfhi(praw.y);

    // ---- transpose via per-wave LDS scratch (C-layout -> row-per-lane) ----
    #pragma unroll
    for (int i = 0; i < 4; ++i)
      myscr[(4 * g + i) * 20 + r16] = accsum[i];
    float acc_t[16];
    #pragma unroll
    for (int c = 0; c < 16; ++c)
      acc_t[c] = myscr[r16 * 20 + c];

    // ---- triangular solve: bf16 wtri rows, uniform-addr broadcast reads ----
    const unsigned short* wt = wtriL[cur];
    #pragma unroll
    for (int k = 0; k < 16; ++k) {
      const uint4 w0 = *(const uint4*)&wt[k * 16];
      const uint4 w1 = *(const uint4*)&wt[k * 16 + 8];
      const unsigned int wd[8] = {w0.x, w0.y, w0.z, w0.w,
                                  w1.x, w1.y, w1.z, w1.w};
      float xk = acc_t[k] + ((k & 1) ? bfhi(wd[k >> 1]) : bflo(wd[k >> 1]));
      float s  = __builtin_amdgcn_rcpf(
          1.f + __builtin_amdgcn_exp2f(xk * -1.44269504088896341f));
      acc_t[k] = s;
      #pragma unroll
      for (int c = k + 1; c < 16; ++c) {
        float wc = (c & 1) ? bfhi(wd[c >> 1]) : bflo(wd[c >> 1]);
        acc_t[c] = __builtin_fmaf(s, wc, acc_t[c]);
      }
    }

    if (b == NBLK - 1) {
      const size_t orow = (size_t)(slab_off + rb + r16) * OUT_DIM;
      #pragma unroll
      for (int i = 0; i < 4; ++i) {
        int oc = 4 * g + i;
        int mi = NMID - OUT_DIM + oc;
        out[orow + oc] = (acc_t[oc] + bias[mi]) * (float)ex[mi];
      }
    } else {
      // pack the 16 new values into the owning middle-chunk register;
      // phase-local 8-iter guard (cm = b>>1 = base + ((b>>1)&7))
      const int cml = (b >> 1) & 7;
      const int vb = 8 * (g & 1);
      uint4 packed;
      packed.x = f2bf(acc_t[vb + 0]) | (f2bf(acc_t[vb + 1]) << 16);
      packed.y = f2bf(acc_t[vb + 2]) | (f2bf(acc_t[vb + 3]) << 16);
      packed.z = f2bf(acc_t[vb + 4]) | (f2bf(acc_t[vb + 5]) << 16);
      packed.w = f2bf(acc_t[vb + 6]) | (f2bf(acc_t[vb + 7]) << 16);
      const bool part = ((g >> 1) == (b & 1));
#define PACKW(base)                                                           \
  {                                                                           \
    _Pragma("unroll")                                                         \
    for (int c2 = 0; c2 < 8; ++c2)                                            \
      if (c2 == cml) {                                                        \
        if (part) sfrag[(base) + c2] = packed;                                \
      }                                                                       \
  }
      if (b < 16) {
        PACKW(0)
      } else if (b < 32) {
        PACKW(8)
      } else {
        PACKW(16)
      }
#undef PACKW
    }

    __syncthreads();   // publish staged B/wtri; prior LDS reads done
  }
#undef STAGE_B
}

// ---------------------------------------------------------------------------
extern "C" void kernel_launch(void* const* d_in, const int* in_sizes, int n_in,
                              void* d_out, int out_size, void* d_ws, size_t ws_size,
                              hipStream_t stream) {
  const float* x      = (const float*)d_in[0];
  const float* weight = (const float*)d_in[1];
  const float* bias   = (const float*)d_in[2];
  const int*   conn   = (const int*)d_in[3];
  const int*   ex     = (const int*)d_in[4];

  char* ws = (char*)d_ws;
  size_t off = 0;
  unsigned short* effX = (unsigned short*)(ws + off); off += (size_t)NMID * INPUT_DIM * 2;
  unsigned short* effM = (unsigned short*)(ws + off); off += (size_t)NMID * MROW * 2;
  float*          cvec = (float*)(ws + off);          off += (size_t)NMID * 4;
  unsigned short* wpk  = (unsigned short*)(ws + off); off += (size_t)NBLK * 256 * 2;
  off = (off + 255) & ~(size_t)255;
  const size_t fixed = off;

  // Pt slab sizing: smallest power-of-two slab count that fits ws.
  int nslabs = 1;
  while (nslabs < 16 &&
         fixed + (size_t)NMID * (BATCH / nslabs) * 2 > ws_size)
    nslabs <<= 1;
  const int slabsz = BATCH / nslabs;
  unsigned short* Pt = (unsigned short*)(ws + fixed);

  prep_efft<<<dim3(16, 13), 256, 0, stream>>>(weight, conn, ex, effX, effM);
  prep_cvec<<<dim3(NMID), 64, 0, stream>>>(effM, weight, conn, ex, bias, cvec);
  prep_wpack<<<dim3(NBLK), 256, 0, stream>>>(weight, conn, ex, cvec, wpk);

  for (int s = 0; s < nslabs; ++s) {
    pgemm<<<dim3(slabsz / 64), 256, 0, stream>>>(
        x, effX, Pt, s * slabsz, slabsz);
    net_main<<<dim3(slabsz / 64), 256, 0, stream>>>(
        Pt, effM, wpk, bias, ex, (float*)d_out, s * slabsz, slabsz);
  }
}